// Round 17
// baseline (35.937 us; speedup 1.0000x reference)
//
#include <hip/hip_runtime.h>

// ShiftGraph: B=8, C=16, H=W=256, d=5 (r=2), 24 shifts.
// Output (flat float32): edges (B, E, 2) then ws (B, E), E = 1557540.
// R17: R16 + (1) 2 output rows/block (512 thr, stage 4 rows -> 2 rows/output),
// (2) ping-pong LDS (16KB x2): ONE barrier per 4-channel chunk, next chunk's
// global loads issued before current chunk's compute. 4 blocks/CU = 32 waves.

#define HH 256
#define WW 256
#define CC 16
#define BB 8
#define HW (HH * WW)
#define EE 1557540

__global__ __launch_bounds__(512) void shiftgraph_kernel(
    const float* __restrict__ x, float* __restrict__ out) {
    __shared__ float lds[2][4096];   // [buf][4ch][4rows][256cols] = 2x16 KB
    const int bid = blockIdx.x;      // 0..1023
    const int b  = bid & 7;          // batch -> XCD
    const int hg = bid >> 3;         // row-pair 0..127
    const int tid = threadIdx.x;     // 0..511
    const int rr = tid >> 8;         // wave-uniform row select
    const int w  = tid & 255;
    const int h  = hg * 2 + rr;

    const float* __restrict__ xb = x + (size_t)b * (CC * HW);

    // staging map: 4096 floats = [cl<4][row<4][col<256]; 2 float4 per thread
    const float* src[2];
    int dst[2];
#pragma unroll
    for (int inst = 0; inst < 2; ++inst) {
        const int flatf = inst * 2048 + tid * 4;
        const int cl  = flatf >> 10;
        const int rem = flatf & 1023;
        const int row = rem >> 8;
        const int col = rem & 255;
        int hr = hg * 2 + row; hr = hr > HH - 1 ? HH - 1 : hr;  // clamp: guarded
        src[inst] = xb + cl * HW + hr * WW + col;
        dst[inst] = flatf;
    }

    // prologue: stage chunk 0 into buf 0
#pragma unroll
    for (int inst = 0; inst < 2; ++inst) {
        const float4 v = *reinterpret_cast<const float4*>(src[inst]);
        *reinterpret_cast<float4*>(&lds[0][dst[inst]]) = v;
        src[inst] += 4 * HW;
    }
    __syncthreads();

    float acc[12];
#pragma unroll
    for (int s2 = 0; s2 < 12; ++s2) acc[s2] = 0.0f;

#pragma unroll
    for (int cc = 0; cc < 4; ++cc) {
        float4 nv0, nv1;
        if (cc < 3) {                       // issue next-chunk loads early
            nv0 = *reinterpret_cast<const float4*>(src[0]);
            nv1 = *reinterpret_cast<const float4*>(src[1]);
            src[0] += 4 * HW; src[1] += 4 * HW;
        }
        const float* __restrict__ buf = lds[cc & 1];
#pragma unroll
        for (int c = 0; c < 4; ++c) {
            const int base = c * 1024 + rr * 256 + w;   // imm offsets below
            const float ctr = buf[base];
            float d;
            d = buf[base + 1] - ctr; acc[0] = fmaf(d, d, acc[0]);   // (0,1)
            d = buf[base + 2] - ctr; acc[1] = fmaf(d, d, acc[1]);   // (0,2)
#pragma unroll
            for (int dj = -2; dj <= 2; ++dj) {
                d = buf[base + 256 + dj] - ctr;                     // (1,dj)
                acc[4 + dj] = fmaf(d, d, acc[4 + dj]);
                d = buf[base + 512 + dj] - ctr;                     // (2,dj)
                acc[9 + dj] = fmaf(d, d, acc[9 + dj]);
            }
        }
        if (cc < 3) {                       // write next chunk, single barrier
            float* __restrict__ nb = lds[(cc + 1) & 1];
            *reinterpret_cast<float4*>(&nb[dst[0]]) = nv0;
            *reinterpret_cast<float4*>(&nb[dst[1]]) = nv1;
            __syncthreads();
        }
    }

    // ---- store burst: own + mirror (pair symmetry) ----
    float* __restrict__ edges = out;                        // (B, E, 2)
    float* __restrict__ wsp   = out + (size_t)BB * EE * 2;  // (B, E)
    const size_t bE = (size_t)b * EE;
    const int posc = h * WW + w;

    int s = 0;
#pragma unroll
    for (int di = 0; di <= 2; ++di) {
#pragma unroll
        for (int dj = (di == 0 ? 1 : -2); dj <= 2; ++dj, ++s) {
            const int i = di + 2, j = dj + 2;
            if (h + di >= HH) continue;              // wave-uniform
            const int w2 = w + dj;
            if (w2 < 0 || w2 >= WW) continue;        // <=2 edge lanes

            const float scale = sqrtf((float)(di * di + dj * dj));
            const float wsv = -acc[s] * scale;

            int offF = 0, offM = 0;                  // compile-time prefixes
#pragma unroll
            for (int m = 0; m < 25; ++m) {
                const int mi = m / 5, mj = m % 5;
                if (mi == 2 && mj == 2) continue;
                const int cm = (HH - (mi < 2 ? 2 - mi : mi - 2)) *
                               (WW - (mj < 2 ? 2 - mj : mj - 2));
                if (m < i * 5 + j) offF += cm;
                if (m < (4 - i) * 5 + (4 - j)) offM += cm;
            }
            const int cww = WW - (dj < 0 ? -dj : dj);
            const int e1 = offF + h * cww + (w - (dj < 0 ? -dj : 0));
            const int e2 = offM + h * cww + (w + (dj < 0 ? dj : 0));
            const int posv = di * WW + dj;

            union { float f[2]; unsigned long long u; } evF, evM;
            evF.f[0] = (float)posc;          evF.f[1] = (float)(posc + posv);
            evM.f[0] = (float)(posc + posv); evM.f[1] = (float)posc;

            __builtin_nontemporal_store(
                evF.u, reinterpret_cast<unsigned long long*>(edges + (bE + e1) * 2));
            __builtin_nontemporal_store(
                evM.u, reinterpret_cast<unsigned long long*>(edges + (bE + e2) * 2));
            __builtin_nontemporal_store(wsv, wsp + bE + e1);
            __builtin_nontemporal_store(wsv, wsp + bE + e2);
        }
    }
}

extern "C" void kernel_launch(void* const* d_in, const int* in_sizes, int n_in,
                              void* d_out, int out_size, void* d_ws, size_t ws_size,
                              hipStream_t stream) {
    const float* x = (const float*)d_in[0];
    float* out = (float*)d_out;
    dim3 block(512);           // 2 rows x 256 cols
    dim3 grid(128 * BB);       // one block per (row-pair, batch)
    shiftgraph_kernel<<<grid, block, 0, stream>>>(x, out);
}

// Round 19
// 33.639 us; speedup vs baseline: 1.0683x; 1.0683x over previous
//
#include <hip/hip_runtime.h>

// ShiftGraph: B=8, C=16, H=W=256, d=5 (r=2), 24 shifts.
// Output (flat float32): edges (B, E, 2) then ws (B, E), E = 1557540.
// R18: R16 (LDS staging in 4-ch chunks, pair symmetry, 2048x256, 1 px/thread)
// with ONE change: nontemporal stores -> PLAIN stores (A/B the NT hint; the
// 7 TB/s fill calibration uses plain allocate-in-L2 stores).

#define HH 256
#define WW 256
#define CC 16
#define BB 8
#define HW (HH * WW)
#define EE 1557540

__global__ __launch_bounds__(256) void shiftgraph_kernel(
    const float* __restrict__ x, float* __restrict__ out) {
    __shared__ float lds[3080];     // [4ch][3rows][256cols] + 8 pad
    const int bid = blockIdx.x;
    const int b = bid & 7;          // batch -> XCD
    const int h = bid >> 3;         // row
    const int w = threadIdx.x;      // col

    const float* __restrict__ xb = x + (size_t)b * (CC * HW);

    // staging map, computed once: 3072 floats = [cl][row][col], cl=flat/768
    const float* src[3];
    int dst[3];
#pragma unroll
    for (int inst = 0; inst < 3; ++inst) {
        const int flatf = inst * 1024 + w * 4;
        const int cl  = flatf / 768;
        const int rem = flatf - cl * 768;
        const int row = rem >> 8;
        const int col = rem & 255;
        int hr = h + row; hr = hr > HH - 1 ? HH - 1 : hr;  // clamp: stores guarded
        src[inst] = xb + cl * HW + hr * WW + col;
        dst[inst] = flatf;
    }

    float acc[12];
#pragma unroll
    for (int s2 = 0; s2 < 12; ++s2) acc[s2] = 0.0f;

    for (int cc = 0; cc < 4; ++cc) {        // 4-channel chunks
        __syncthreads();
#pragma unroll
        for (int inst = 0; inst < 3; ++inst) {
            const float4 v = *reinterpret_cast<const float4*>(src[inst]);
            *reinterpret_cast<float4*>(&lds[dst[inst]]) = v;
            src[inst] += 4 * HW;
        }
        __syncthreads();
#pragma unroll
        for (int c = 0; c < 4; ++c) {
            const int base = c * 768 + w;   // addr = w*4 + compile-time imm
            const float ctr = lds[base];
            float d;
            d = lds[base + 1] - ctr; acc[0] = fmaf(d, d, acc[0]);   // (0,1)
            d = lds[base + 2] - ctr; acc[1] = fmaf(d, d, acc[1]);   // (0,2)
#pragma unroll
            for (int dj = -2; dj <= 2; ++dj) {
                d = lds[base + 256 + dj] - ctr;                     // (1,dj)
                acc[4 + dj] = fmaf(d, d, acc[4 + dj]);
                d = lds[base + 512 + dj] - ctr;                     // (2,dj)
                acc[9 + dj] = fmaf(d, d, acc[9 + dj]);
            }
        }
    }

    // ---- store burst: own + mirror (R11 addressing), PLAIN stores ----
    float* __restrict__ edges = out;                        // (B, E, 2)
    float* __restrict__ wsp   = out + (size_t)BB * EE * 2;  // (B, E)
    const size_t bE = (size_t)b * EE;
    const int posc = h * WW + w;

    int s = 0;
#pragma unroll
    for (int di = 0; di <= 2; ++di) {
#pragma unroll
        for (int dj = (di == 0 ? 1 : -2); dj <= 2; ++dj, ++s) {
            const int i = di + 2, j = dj + 2;
            if (h + di >= HH) continue;              // uniform across block
            const int w2 = w + dj;
            if (w2 < 0 || w2 >= WW) continue;        // <=2 edge lanes diverge

            const float scale = sqrtf((float)(di * di + dj * dj));
            const float wsv = -acc[s] * scale;

            int offF = 0, offM = 0;                  // compile-time prefixes
#pragma unroll
            for (int m = 0; m < 25; ++m) {
                const int mi = m / 5, mj = m % 5;
                if (mi == 2 && mj == 2) continue;
                const int cm = (HH - (mi < 2 ? 2 - mi : mi - 2)) *
                               (WW - (mj < 2 ? 2 - mj : mj - 2));
                if (m < i * 5 + j) offF += cm;
                if (m < (4 - i) * 5 + (4 - j)) offM += cm;
            }
            const int cww = WW - (dj < 0 ? -dj : dj);
            const int e1 = offF + h * cww + (w - (dj < 0 ? -dj : 0));
            const int e2 = offM + h * cww + (w + (dj < 0 ? dj : 0));
            const int posv = di * WW + dj;

            *reinterpret_cast<float2*>(edges + (bE + e1) * 2) =
                make_float2((float)posc, (float)(posc + posv));
            *reinterpret_cast<float2*>(edges + (bE + e2) * 2) =
                make_float2((float)(posc + posv), (float)posc);
            wsp[bE + e1] = wsv;
            wsp[bE + e2] = wsv;
        }
    }
}

extern "C" void kernel_launch(void* const* d_in, const int* in_sizes, int n_in,
                              void* d_out, int out_size, void* d_ws, size_t ws_size,
                              hipStream_t stream) {
    const float* x = (const float*)d_in[0];
    float* out = (float*)d_out;
    dim3 block(WW);            // one thread per column
    dim3 grid(HH * BB);        // one block per (row, batch)
    shiftgraph_kernel<<<grid, block, 0, stream>>>(x, out);
}